// Round 16
// baseline (766.712 us; speedup 1.0000x reference)
//
#include <hip/hip_runtime.h>

#define HID   24
#define T_LEN 4096
#define BATCH 1024
#define NB    2                  // batches per block (one per 32-lane half)
#define K     32                 // timesteps per chunk (pipeline skew per layer)
#define NC    (T_LEN / K)        // 128 active chunks per layer
#define CTOT  (NC + 2)           // 130 ticks (3-layer skew)
#define TPB   192                // 3 waves: wave w == layer w
#define PS    32                 // padded partial-row stride (f32 elems)

typedef __attribute__((ext_vector_type(2))) _Float16 h2v;
typedef __attribute__((ext_vector_type(2))) unsigned int uint2v;

#if __has_builtin(__builtin_amdgcn_fdot2)
__device__ __forceinline__ float dot2f(int p, int w, float acc) {
    return __builtin_amdgcn_fdot2(__builtin_bit_cast(h2v, p),
                                  __builtin_bit_cast(h2v, w), acc, false);
}
#else
__device__ __forceinline__ float dot2f(int p, int w, float acc) {
    h2v a = __builtin_bit_cast(h2v, p), b = __builtin_bit_cast(h2v, w);
    acc = fmaf((float)a.x, (float)b.x, acc);
    return fmaf((float)a.y, (float)b.y, acc);
}
#endif

__device__ __forceinline__ float dot4(const float4 a, const float4 b, float acc) {
    acc = fmaf(a.x, b.x, acc);
    acc = fmaf(a.y, b.y, acc);
    acc = fmaf(a.z, b.z, acc);
    return fmaf(a.w, b.w, acc);
}

// DPP row-rotate by N within 16-lane rows (VALU pipe) — validated r10/r11/r14
template<int N> __device__ __forceinline__ int rr(int v) {
    return __builtin_amdgcn_mov_dpp(v, 0x120 + N, 0xF, 0xF, false);
}
// quad_perm [1,0,3,2]: neighbor swap within pairs — validated r10/r11/r14
__device__ __forceinline__ int qp_nbr(int v) {
    return __builtin_amdgcn_mov_dpp(v, 0xB1, 0xF, 0xF, false);
}

#define PKF(A_, B_)                                                                 \
    (((int)__builtin_bit_cast(unsigned short, (_Float16)(B_)) << 16) |              \
     (int)__builtin_bit_cast(unsigned short, (_Float16)(A_)))

// weight pair for pair index m, odd-lane half swap (validated r10/r11/r14)
__device__ __forceinline__ int pkw(const float* row, int m, int par) {
    float wl = row[2 * m], wh = row[2 * m + 1];
    if (par) { float t = wl; wl = wh; wh = t; }
    return PKF(wl, wh);
}

// 12 gather-order weight dwords for one 24-wide row (validated r10/r11/r14)
__device__ __forceinline__ void build_g(const float* row, int lane, int dir,
                                        int par, int* g) {
    #pragma unroll
    for (int k = 0; k < 12; ++k) {
        const int r = (k < 8) ? (2 * k) : (2 * (k - 8));
        const int s = ((lane & 15) + dir * r) & 15;
        const int m = (k < 8) ? (s >> 1) : (8 + ((s >> 1) & 3));
        g[k] = pkw(row, m, par);
    }
}

template<bool USE_BP>
__device__ __forceinline__ void run_rnn(
    const float* __restrict__ x, const float* __restrict__ h_in,
    const float* __restrict__ Wih0, const float* __restrict__ bih0,
    const float* __restrict__ Whh0, const float* __restrict__ bhh0,
    const float* __restrict__ Wih1, const float* __restrict__ bih1,
    const float* __restrict__ Whh1, const float* __restrict__ bhh1,
    const float* __restrict__ Wih2, const float* __restrict__ bih2,
    const float* __restrict__ Whh2, const float* __restrict__ bhh2,
    const float* __restrict__ W1,   const float* __restrict__ b1,
    const float* __restrict__ W2,   const float* __restrict__ b2,
    float* __restrict__ out, const int dir, const bool flip,
    float* part1, float* part2, float (*h2f)[HID], float (*mbuf)[HID])
{
    const int tid  = threadIdx.x;
    const int l    = tid >> 6;        // wave == layer
    const int lane = tid & 63;
    const int bl   = lane >> 5;       // batch half
    const int jj   = lane & 31;
    const bool act = (jj < HID);
    const int uL   = act ? jj : (jj - 8);   // pad lanes duplicate units 16-23
    const int par  = lane & 1;
    const int bg   = blockIdx.x * NB + bl;
    const int alo  = (((lane & 32) | (lane & 15)) << 2);       // bpermute fallback
    const int ahi  = (((lane & 32) | 16 | (lane & 15)) << 2);

    // ---- weights (gather order): own row + downstream partial row ----
    int gOwn[12], gPart[12];
    float wx0 = 0.f, bias;
    if (l == 0) {
        build_g(Whh0 + uL * HID, lane, dir, par, gOwn);
        build_g(Wih1 + uL * HID, lane, dir, par, gPart);   // part1 = Wih1 . h0
        wx0  = Wih0[uL];
        bias = bih0[uL] + bhh0[uL];
    } else if (l == 1) {
        build_g(Whh1 + uL * HID, lane, dir, par, gOwn);
        build_g(Wih2 + uL * HID, lane, dir, par, gPart);   // part2 = Wih2 . h1
        bias = bih1[uL] + bhh1[uL];
    } else {
        build_g(Whh2 + uL * HID, lane, dir, par, gOwn);
        #pragma unroll
        for (int k = 0; k < 12; ++k) gPart[k] = 0;
        bias = bih2[uL] + bhh2[uL];
    }

    float cur = h_in[(l * BATCH + bg) * HID + uL];

#define GATHER(CF_, R_) do {                                                        \
    int hc_ = (int)(unsigned)__builtin_bit_cast(unsigned short, (_Float16)(CF_));   \
    int pk_ = (qp_nbr(hc_) << 16) | hc_;                                            \
    int ea_, eb_;                                                                   \
    if constexpr (USE_BP) {                                                         \
        ea_ = __builtin_amdgcn_ds_bpermute(alo, pk_);                               \
        eb_ = __builtin_amdgcn_ds_bpermute(ahi, pk_);                               \
    } else {                                                                        \
        uint2v s_ = __builtin_amdgcn_permlane16_swap((unsigned)pk_, (unsigned)pk_,  \
                                                     false, false);                 \
        ea_ = flip ? (int)s_.y : (int)s_.x;                                         \
        eb_ = flip ? (int)s_.x : (int)s_.y;                                         \
    }                                                                               \
    R_[0] = ea_;         R_[1] = rr<2>(ea_);   R_[2] = rr<4>(ea_);                  \
    R_[3] = rr<6>(ea_);  R_[4] = rr<8>(ea_);   R_[5] = rr<10>(ea_);                 \
    R_[6] = rr<12>(ea_); R_[7] = rr<14>(ea_);                                       \
    R_[8] = eb_;         R_[9] = rr<2>(eb_);   R_[10] = rr<4>(eb_);                 \
    R_[11] = rr<6>(eb_);                                                            \
} while (0)

#define DOT12G(R_, W_, A0_, A1_)                                                    \
    A0_ = dot2f(R_[0], W_[0], A0_);   A1_ = dot2f(R_[1], W_[1], A1_);               \
    A0_ = dot2f(R_[2], W_[2], A0_);   A1_ = dot2f(R_[3], W_[3], A1_);               \
    A0_ = dot2f(R_[4], W_[4], A0_);   A1_ = dot2f(R_[5], W_[5], A1_);               \
    A0_ = dot2f(R_[6], W_[6], A0_);   A1_ = dot2f(R_[7], W_[7], A1_);               \
    A0_ = dot2f(R_[8], W_[8], A0_);   A1_ = dot2f(R_[9], W_[9], A1_);               \
    A0_ = dot2f(R_[10], W_[10], A0_); A1_ = dot2f(R_[11], W_[11], A1_);

    int R[12];
    GATHER(cur, R);

    // ---- x quads in registers (l0): 8 current + 8 prefetch ----
    const float* xrow = x + (size_t)bg * T_LEN;
    float4 xq[8], xn[8];
    if (l == 0) {
        const float4* xr = (const float4*)xrow;
        #pragma unroll
        for (int q = 0; q < 8; ++q) xq[q] = xr[q];
    }
#define XV(S)                                                                       \
    (((S) & 3) == 0 ? xq[(S) >> 2].x : ((S) & 3) == 1 ? xq[(S) >> 2].y              \
   : ((S) & 3) == 2 ? xq[(S) >> 2].z : xq[(S) >> 2].w)

    __syncthreads();

    // ---- chunked, layer-skewed scan: tick c; l0->chunk c, l1->c-1, l2->c-2 ----
    for (int c = 0; c < CTOT; ++c) {
        const int wp = c & 1, rp = wp ^ 1;
        if (l == 0) {
            if (c < NC) {
                const bool pf = (c + 1 < NC);
                if (pf) {
                    const float4* xr = (const float4*)(xrow + (size_t)(c + 1) * K);
                    #pragma unroll
                    for (int q = 0; q < 8; ++q) xn[q] = xr[q];
                }
                float* dst = part1 + ((size_t)(wp * NB + bl) * K) * PS;
                #pragma unroll
                for (int s = 0; s < K; ++s) {
                    float a0 = fmaf(wx0, XV(s), bias), a1 = 0.f;
                    DOT12G(R, gOwn, a0, a1);
                    cur = fmaxf(a0 + a1, 0.f);
                    GATHER(cur, R);
                    float p0 = 0.f, p1 = 0.f;
                    DOT12G(R, gPart, p0, p1);          // Wih1 . h0(t), off-chain
                    dst[s * PS + jj] = p0 + p1;
                }
                if (pf) {
                    #pragma unroll
                    for (int q = 0; q < 8; ++q) xq[q] = xn[q];
                }
            }
        } else if (l == 1) {
            if (c >= 1 && c < 1 + NC) {
                const float* src = part1 + ((size_t)(rp * NB + bl) * K) * PS;
                float* dst = part2 + ((size_t)(wp * NB + bl) * K) * PS;
                #pragma unroll
                for (int s = 0; s < K; ++s) {
                    const float pin = src[s * PS + jj];   // Wih1 . h0(t)
                    float a0 = pin + bias, a1 = 0.f;
                    DOT12G(R, gOwn, a0, a1);
                    cur = fmaxf(a0 + a1, 0.f);
                    GATHER(cur, R);
                    float p0 = 0.f, p1 = 0.f;
                    DOT12G(R, gPart, p0, p1);          // Wih2 . h1(t), off-chain
                    dst[s * PS + jj] = p0 + p1;
                }
            }
        } else {
            if (c >= 2 && c < 2 + NC) {
                const float* src = part2 + ((size_t)(rp * NB + bl) * K) * PS;
                #pragma unroll
                for (int s = 0; s < K; ++s) {
                    const float pin = src[s * PS + jj];   // Wih2 . h1(t)
                    float a0 = pin + bias, a1 = 0.f;
                    DOT12G(R, gOwn, a0, a1);
                    cur = fmaxf(a0 + a1, 0.f);
                    GATHER(cur, R);
                }
            }
        }
        __syncthreads();
    }
#undef XV
#undef DOT12G
#undef GATHER

    // ---- h_final from f32 running values ----
    if (act) out[BATCH + (size_t)(l * BATCH + bg) * HID + uL] = cur;

    // ---- MLP head on h2(T-1) ----
    if (l == 2 && act) h2f[bl][uL] = cur;
    __syncthreads();
    if (l == 2 && act) {
        const float4* w1r = (const float4*)(W1 + uL * HID);
        const float4* hv  = (const float4*)&h2f[bl][0];
        float a = b1[uL];
        a = dot4(w1r[0], hv[0], a); a = dot4(w1r[1], hv[1], a);
        a = dot4(w1r[2], hv[2], a); a = dot4(w1r[3], hv[3], a);
        a = dot4(w1r[4], hv[4], a); a = dot4(w1r[5], hv[5], a);
        mbuf[bl][uL] = fmaxf(a, 0.f);
    }
    __syncthreads();
    if (l == 2 && jj == 0) {
        float a = b2[0];
        #pragma unroll
        for (int k = 0; k < HID; ++k) a = fmaf(W2[k], mbuf[bl][k], a);
        out[bg] = fmaxf(a, 0.f);
    }
}

__global__ __launch_bounds__(TPB, 1) void rnn_part_kernel(
    const float* __restrict__ x, const float* __restrict__ h_in,
    const float* __restrict__ Wih0, const float* __restrict__ bih0,
    const float* __restrict__ Whh0, const float* __restrict__ bhh0,
    const float* __restrict__ Wih1, const float* __restrict__ bih1,
    const float* __restrict__ Whh1, const float* __restrict__ bhh1,
    const float* __restrict__ Wih2, const float* __restrict__ bih2,
    const float* __restrict__ Whh2, const float* __restrict__ bhh2,
    const float* __restrict__ W1,   const float* __restrict__ b1,
    const float* __restrict__ W2,   const float* __restrict__ b2,
    float* __restrict__ out)
{
    __shared__ __align__(16) float part1[2 * NB * K * PS];   // Wih1 . h0(t)
    __shared__ __align__(16) float part2[2 * NB * K * PS];   // Wih2 . h1(t)
    __shared__ float h2f[NB][HID];
    __shared__ float mbuf[NB][HID];

    const int lane = threadIdx.x & 63;
    const int d0 = __builtin_amdgcn_readfirstlane(rr<2>(lane));
    const int dir = (d0 == 2) ? 1 : -1;

#if __has_builtin(__builtin_amdgcn_permlane16_swap)
    uint2v sw = __builtin_amdgcn_permlane16_swap((unsigned)lane, (unsigned)lane,
                                                 false, false);
    const int s0  = __builtin_amdgcn_readlane((int)sw.x, 0);
    const int s16 = __builtin_amdgcn_readlane((int)sw.x, 16);
    const bool ok   = (s0 == 0 && s16 == 0) || (s0 == 16 && s16 == 16);
    const bool flip = (s0 == 16);
    if (ok) {
        run_rnn<false>(x, h_in, Wih0, bih0, Whh0, bhh0, Wih1, bih1, Whh1, bhh1,
                       Wih2, bih2, Whh2, bhh2, W1, b1, W2, b2, out,
                       dir, flip, part1, part2, h2f, mbuf);
    } else {
        run_rnn<true>(x, h_in, Wih0, bih0, Whh0, bhh0, Wih1, bih1, Whh1, bhh1,
                      Wih2, bih2, Whh2, bhh2, W1, b1, W2, b2, out,
                      dir, false, part1, part2, h2f, mbuf);
    }
#else
    run_rnn<true>(x, h_in, Wih0, bih0, Whh0, bhh0, Wih1, bih1, Whh1, bhh1,
                  Wih2, bih2, Whh2, bhh2, W1, b1, W2, b2, out,
                  dir, false, part1, part2, h2f, mbuf);
#endif
}

extern "C" void kernel_launch(void* const* d_in, const int* in_sizes, int n_in,
                              void* d_out, int out_size, void* d_ws, size_t ws_size,
                              hipStream_t stream) {
    const float* x    = (const float*)d_in[0];
    const float* h_in = (const float*)d_in[1];
    const float* Wih0 = (const float*)d_in[2];
    const float* bih0 = (const float*)d_in[3];
    const float* Whh0 = (const float*)d_in[4];
    const float* bhh0 = (const float*)d_in[5];
    const float* Wih1 = (const float*)d_in[6];
    const float* bih1 = (const float*)d_in[7];
    const float* Whh1 = (const float*)d_in[8];
    const float* bhh1 = (const float*)d_in[9];
    const float* Wih2 = (const float*)d_in[10];
    const float* bih2 = (const float*)d_in[11];
    const float* Whh2 = (const float*)d_in[12];
    const float* bhh2 = (const float*)d_in[13];
    const float* W1   = (const float*)d_in[14];
    const float* b1   = (const float*)d_in[15];
    const float* W2   = (const float*)d_in[16];
    const float* b2   = (const float*)d_in[17];
    float* out = (float*)d_out;

    dim3 grid(BATCH / NB);   // 512 blocks -> 2 blocks/CU, 6 waves/CU
    dim3 block(TPB);         // 3 waves (wave == layer)
    hipLaunchKernelGGL(rnn_part_kernel, grid, block, 0, stream,
                       x, h_in, Wih0, bih0, Whh0, bhh0,
                       Wih1, bih1, Whh1, bhh1, Wih2, bih2, Whh2, bhh2,
                       W1, b1, W2, b2, out);
}

// Round 17
// 576.352 us; speedup vs baseline: 1.3303x; 1.3303x over previous
//
#include <hip/hip_runtime.h>

#define HID   24
#define T_LEN 4096
#define BATCH 1024
#define NB    2                  // batches per block (one per 32-lane half)
#define K     32                 // timesteps per chunk (pipeline skew per layer)
#define NC    (T_LEN / K)        // 128 active chunks per layer
#define CTOT  (NC + 2)           // 130 ticks (3-layer skew)
#define TPB   192                // 3 waves: wave w == layer w
#define PS    32                 // padded row stride (elements)

typedef __attribute__((ext_vector_type(2))) _Float16 h2v;
typedef __attribute__((ext_vector_type(4))) int      int4v;

#if __has_builtin(__builtin_amdgcn_fdot2)
__device__ __forceinline__ float dot2f(int p, int w, float acc) {
    return __builtin_amdgcn_fdot2(__builtin_bit_cast(h2v, p),
                                  __builtin_bit_cast(h2v, w), acc, false);
}
#else
__device__ __forceinline__ float dot2f(int p, int w, float acc) {
    h2v a = __builtin_bit_cast(h2v, p), b = __builtin_bit_cast(h2v, w);
    acc = fmaf((float)a.x, (float)b.x, acc);
    return fmaf((float)a.y, (float)b.y, acc);
}
#endif

__device__ __forceinline__ float dot4(const float4 a, const float4 b, float acc) {
    acc = fmaf(a.x, b.x, acc);
    acc = fmaf(a.y, b.y, acc);
    acc = fmaf(a.z, b.z, acc);
    return fmaf(a.w, b.w, acc);
}

// pack two f32 -> packed f16 pair dword
#define PKF(A_, B_)                                                                 \
    (((int)__builtin_bit_cast(unsigned short, (_Float16)(B_)) << 16) |              \
     (int)__builtin_bit_cast(unsigned short, (_Float16)(A_)))

__global__ __launch_bounds__(TPB, 1) void rnn_bal2_kernel(
    const float* __restrict__ x,     // [B, T]
    const float* __restrict__ h_in,  // [3, B, 24]
    const float* __restrict__ Wih0, const float* __restrict__ bih0,
    const float* __restrict__ Whh0, const float* __restrict__ bhh0,
    const float* __restrict__ Wih1, const float* __restrict__ bih1,
    const float* __restrict__ Whh1, const float* __restrict__ bhh1,
    const float* __restrict__ Wih2, const float* __restrict__ bih2,
    const float* __restrict__ Whh2, const float* __restrict__ bhh2,
    const float* __restrict__ W1,   const float* __restrict__ b1,
    const float* __restrict__ W2,   const float* __restrict__ b2,
    float* __restrict__ out)         // [1024 (y)] ++ [3*1024*24 (h_final)]
{
    // per-layer private own rows, step ping-pong (only that layer's wave touches them)
    __shared__ __align__(16) _Float16 row0[2][NB][PS];
    __shared__ __align__(16) _Float16 row1[2][NB][PS];
    __shared__ __align__(16) _Float16 row2[2][NB][PS];
    // f32 input partials, tick parity: part1 = Wih1.h0(t), part2 = Wih2.h1(t)
    __shared__ __align__(16) float part1[2][NB][K][PS];
    __shared__ __align__(16) float part2[2][NB][K][PS];
    __shared__ float h2f[NB][HID];
    __shared__ float mbuf[NB][HID];

    const int tid  = threadIdx.x;
    const int l    = tid >> 6;        // wave == layer
    const int lane = tid & 63;
    const int bl   = lane >> 5;       // batch half
    const int jj   = lane & 31;
    const bool act = (jj < HID);
    const int uL   = act ? jj : (jj - 8);   // pad lanes duplicate units 16-23
    const int bg   = blockIdx.x * NB + bl;

    // ---- packed-f16 weights in named int4v registers (natural pair order) ----
    int4v whA, whB, whC;              // own-h row for this wave's layer
    int4v wiA = {0,0,0,0}, wiB = {0,0,0,0}, wiC = {0,0,0,0};
    // l0: wi* = Wih1 row (part1 weights); l1: wi* = Wih2 row (part2 weights)
    float wx0 = 0.f, bias;

#define MK3(ROW, DA, DB, DC) do {                                                   \
        DA = (int4v){PKF((ROW)[0], (ROW)[1]),   PKF((ROW)[2], (ROW)[3]),            \
                     PKF((ROW)[4], (ROW)[5]),   PKF((ROW)[6], (ROW)[7])};           \
        DB = (int4v){PKF((ROW)[8], (ROW)[9]),   PKF((ROW)[10], (ROW)[11]),          \
                     PKF((ROW)[12], (ROW)[13]), PKF((ROW)[14], (ROW)[15])};         \
        DC = (int4v){PKF((ROW)[16], (ROW)[17]), PKF((ROW)[18], (ROW)[19]),          \
                     PKF((ROW)[20], (ROW)[21]), PKF((ROW)[22], (ROW)[23])};         \
    } while (0)

    if (l == 0) {
        MK3(Whh0 + uL * HID, whA, whB, whC);
        MK3(Wih1 + uL * HID, wiA, wiB, wiC);
        wx0  = Wih0[uL];
        bias = bih0[uL] + bhh0[uL];
    } else if (l == 1) {
        MK3(Whh1 + uL * HID, whA, whB, whC);
        MK3(Wih2 + uL * HID, wiA, wiB, wiC);
        bias = bih1[uL] + bhh1[uL];
    } else {
        MK3(Whh2 + uL * HID, whA, whB, whC);
        bias = bih2[uL] + bhh2[uL];
    }
#undef MK3

    float cur = h_in[(l * BATCH + bg) * HID + uL];

    // seed: each layer's own row, parity 1 (read at s=0 of its first chunk)
    if (l == 0) row0[1][bl][jj] = (_Float16)cur;
    if (l == 1) row1[1][bl][jj] = (_Float16)cur;
    if (l == 2) row2[1][bl][jj] = (_Float16)cur;

    // ---- x quads in registers (l0): 8 current + 8 prefetch ----
    const float* xrow = x + (size_t)bg * T_LEN;
    float4 xq[8], xn[8];
    if (l == 0) {
        const float4* xr = (const float4*)xrow;
        #pragma unroll
        for (int q = 0; q < 8; ++q) xq[q] = xr[q];
    }
#define XV(S)                                                                       \
    (((S) & 3) == 0 ? xq[(S) >> 2].x : ((S) & 3) == 1 ? xq[(S) >> 2].y              \
   : ((S) & 3) == 2 ? xq[(S) >> 2].z : xq[(S) >> 2].w)

// 12 packed dots of row triple (V0,V1,V2) vs weight triple into A0,A1
#define DOT12(V0_, V1_, V2_, W0_, W1_, W2_, A0_, A1_)                               \
    A0_ = dot2f(V0_.x, W0_.x, A0_); A1_ = dot2f(V0_.y, W0_.y, A1_);                 \
    A0_ = dot2f(V0_.z, W0_.z, A0_); A1_ = dot2f(V0_.w, W0_.w, A1_);                 \
    A0_ = dot2f(V1_.x, W1_.x, A0_); A1_ = dot2f(V1_.y, W1_.y, A1_);                 \
    A0_ = dot2f(V1_.z, W1_.z, A0_); A1_ = dot2f(V1_.w, W1_.w, A1_);                 \
    A0_ = dot2f(V2_.x, W2_.x, A0_); A1_ = dot2f(V2_.y, W2_.y, A1_);                 \
    A0_ = dot2f(V2_.z, W2_.z, A0_); A1_ = dot2f(V2_.w, W2_.w, A1_);

    __syncthreads();

    // ---- chunked, layer-skewed scan: tick c; l0->chunk c, l1->c-1, l2->c-2 ----
    for (int c = 0; c < CTOT; ++c) {
        const int wp = c & 1, rp = wp ^ 1;
        if (l == 0) {
            if (c < NC) {
                const bool pf = (c + 1 < NC);
                if (pf) {
                    const float4* xr = (const float4*)(xrow + (size_t)(c + 1) * K);
                    #pragma unroll
                    for (int q = 0; q < 8; ++q) xn[q] = xr[q];
                }
                float* dst = &part1[wp][bl][0][0];
                #pragma unroll
                for (int s = 0; s < K; ++s) {
                    const int4v* own = (const int4v*)&row0[(s + 1) & 1][bl][0];
                    const int4v o0 = own[0], o1 = own[1], o2 = own[2]; // h0(t-1)
                    float a0 = fmaf(wx0, XV(s), bias), a1 = 0.f;
                    DOT12(o0, o1, o2, whA, whB, whC, a0, a1);
                    cur = fmaxf(a0 + a1, 0.f);
                    row0[s & 1][bl][jj] = (_Float16)cur;
                    if (s > 0) {                       // part1 for step t-1 (off-chain)
                        float p0 = 0.f, p1 = 0.f;
                        DOT12(o0, o1, o2, wiA, wiB, wiC, p0, p1);
                        dst[(s - 1) * PS + jj] = p0 + p1;
                    }
                }
                {   // epilogue: part1 for the chunk's last step (one RAW per chunk)
                    const int4v* own = (const int4v*)&row0[1][bl][0];
                    const int4v o0 = own[0], o1 = own[1], o2 = own[2];
                    float p0 = 0.f, p1 = 0.f;
                    DOT12(o0, o1, o2, wiA, wiB, wiC, p0, p1);
                    dst[(K - 1) * PS + jj] = p0 + p1;
                }
                if (pf) {
                    #pragma unroll
                    for (int q = 0; q < 8; ++q) xq[q] = xn[q];
                }
            }
        } else if (l == 1) {
            if (c >= 1 && c < 1 + NC) {
                const float* srcp = &part1[rp][bl][0][0];
                float* dstp = &part2[wp][bl][0][0];
                #pragma unroll
                for (int s = 0; s < K; ++s) {
                    const int4v* own = (const int4v*)&row1[(s + 1) & 1][bl][0];
                    const int4v o0 = own[0], o1 = own[1], o2 = own[2]; // h1(t-1)
                    const float pin = srcp[s * PS + jj];               // Wih1.h0(t)
                    float a0 = pin + bias, a1 = 0.f;
                    DOT12(o0, o1, o2, whA, whB, whC, a0, a1);
                    cur = fmaxf(a0 + a1, 0.f);
                    row1[s & 1][bl][jj] = (_Float16)cur;
                    if (s > 0) {                       // part2 for step t-1 (off-chain)
                        float p0 = 0.f, p1 = 0.f;
                        DOT12(o0, o1, o2, wiA, wiB, wiC, p0, p1);
                        dstp[(s - 1) * PS + jj] = p0 + p1;
                    }
                }
                {   // epilogue: part2 for the chunk's last step
                    const int4v* own = (const int4v*)&row1[1][bl][0];
                    const int4v o0 = own[0], o1 = own[1], o2 = own[2];
                    float p0 = 0.f, p1 = 0.f;
                    DOT12(o0, o1, o2, wiA, wiB, wiC, p0, p1);
                    dstp[(K - 1) * PS + jj] = p0 + p1;
                }
            }
        } else {
            if (c >= 2 && c < 2 + NC) {
                const float* srcp = &part2[rp][bl][0][0];
                #pragma unroll
                for (int s = 0; s < K; ++s) {
                    const int4v* own = (const int4v*)&row2[(s + 1) & 1][bl][0];
                    const int4v o0 = own[0], o1 = own[1], o2 = own[2]; // h2(t-1)
                    const float pin = srcp[s * PS + jj];               // Wih2.h1(t)
                    float a0 = pin + bias, a1 = 0.f;
                    DOT12(o0, o1, o2, whA, whB, whC, a0, a1);
                    cur = fmaxf(a0 + a1, 0.f);
                    row2[s & 1][bl][jj] = (_Float16)cur;
                }
            }
        }
        __syncthreads();
    }
#undef XV
#undef DOT12

    // ---- h_final from f32 running values ----
    if (act) out[BATCH + (size_t)(l * BATCH + bg) * HID + uL] = cur;

    // ---- MLP head on h2(T-1) ----
    if (l == 2 && act) h2f[bl][uL] = cur;
    __syncthreads();
    if (l == 2 && act) {
        const float4* w1r = (const float4*)(W1 + uL * HID);
        const float4* hv  = (const float4*)&h2f[bl][0];
        float a = b1[uL];
        a = dot4(w1r[0], hv[0], a); a = dot4(w1r[1], hv[1], a);
        a = dot4(w1r[2], hv[2], a); a = dot4(w1r[3], hv[3], a);
        a = dot4(w1r[4], hv[4], a); a = dot4(w1r[5], hv[5], a);
        mbuf[bl][uL] = fmaxf(a, 0.f);
    }
    __syncthreads();
    if (l == 2 && jj == 0) {
        float a = b2[0];
        #pragma unroll
        for (int k = 0; k < HID; ++k) a = fmaf(W2[k], mbuf[bl][k], a);
        out[bg] = fmaxf(a, 0.f);
    }
}

extern "C" void kernel_launch(void* const* d_in, const int* in_sizes, int n_in,
                              void* d_out, int out_size, void* d_ws, size_t ws_size,
                              hipStream_t stream) {
    const float* x    = (const float*)d_in[0];
    const float* h_in = (const float*)d_in[1];
    const float* Wih0 = (const float*)d_in[2];
    const float* bih0 = (const float*)d_in[3];
    const float* Whh0 = (const float*)d_in[4];
    const float* bhh0 = (const float*)d_in[5];
    const float* Wih1 = (const float*)d_in[6];
    const float* bih1 = (const float*)d_in[7];
    const float* Whh1 = (const float*)d_in[8];
    const float* bhh1 = (const float*)d_in[9];
    const float* Wih2 = (const float*)d_in[10];
    const float* bih2 = (const float*)d_in[11];
    const float* Whh2 = (const float*)d_in[12];
    const float* bhh2 = (const float*)d_in[13];
    const float* W1   = (const float*)d_in[14];
    const float* b1   = (const float*)d_in[15];
    const float* W2   = (const float*)d_in[16];
    const float* b2   = (const float*)d_in[17];
    float* out = (float*)d_out;

    dim3 grid(BATCH / NB);   // 512 blocks -> 2 blocks/CU, 6 waves/CU
    dim3 block(TPB);         // 3 waves (wave == layer)
    hipLaunchKernelGGL(rnn_bal2_kernel, grid, block, 0, stream,
                       x, h_in, Wih0, bih0, Whh0, bhh0,
                       Wih1, bih1, Whh1, bhh1, Wih2, bih2, Whh2, bhh2,
                       W1, b1, W2, b2, out);
}

// Round 18
// 510.053 us; speedup vs baseline: 1.5032x; 1.1300x over previous
//
#include <hip/hip_runtime.h>

#define HID   24
#define T_LEN 4096
#define BATCH 1024
#define NB    2                  // batches per block (one per 32-lane half)
#define K     32                 // timesteps per chunk (pipeline skew per layer)
#define NC    (T_LEN / K)        // 128 active chunks per layer
#define CTOT  (NC + 2)           // 130 ticks (3-layer skew)
#define TPB   192                // 3 waves: wave w == layer w
#define PS    32                 // padded row stride (elements)

typedef __attribute__((ext_vector_type(2))) _Float16 h2v;
typedef __attribute__((ext_vector_type(4))) int      int4v;

#if __has_builtin(__builtin_amdgcn_fdot2)
__device__ __forceinline__ float dot2f(int p, int w, float acc) {
    return __builtin_amdgcn_fdot2(__builtin_bit_cast(h2v, p),
                                  __builtin_bit_cast(h2v, w), acc, false);
}
#else
__device__ __forceinline__ float dot2f(int p, int w, float acc) {
    h2v a = __builtin_bit_cast(h2v, p), b = __builtin_bit_cast(h2v, w);
    acc = fmaf((float)a.x, (float)b.x, acc);
    return fmaf((float)a.y, (float)b.y, acc);
}
#endif

__device__ __forceinline__ float dot4(const float4 a, const float4 b, float acc) {
    acc = fmaf(a.x, b.x, acc);
    acc = fmaf(a.y, b.y, acc);
    acc = fmaf(a.z, b.z, acc);
    return fmaf(a.w, b.w, acc);
}

// pack two f32 -> packed f16 pair dword
#define PKF(A_, B_)                                                                 \
    (((int)__builtin_bit_cast(unsigned short, (_Float16)(B_)) << 16) |              \
     (int)__builtin_bit_cast(unsigned short, (_Float16)(A_)))

__global__ __launch_bounds__(TPB, 1) void rnn_ra_kernel(
    const float* __restrict__ x,     // [B, T]
    const float* __restrict__ h_in,  // [3, B, 24]
    const float* __restrict__ Wih0, const float* __restrict__ bih0,
    const float* __restrict__ Whh0, const float* __restrict__ bhh0,
    const float* __restrict__ Wih1, const float* __restrict__ bih1,
    const float* __restrict__ Whh1, const float* __restrict__ bhh1,
    const float* __restrict__ Wih2, const float* __restrict__ bih2,
    const float* __restrict__ Whh2, const float* __restrict__ bhh2,
    const float* __restrict__ W1,   const float* __restrict__ b1,
    const float* __restrict__ W2,   const float* __restrict__ b2,
    float* __restrict__ out)         // [1024 (y)] ++ [3*1024*24 (h_final)]
{
    // l0/l2 own rows: step ping-pong, wave-private
    __shared__ __align__(16) _Float16 row0[2][NB][PS];
    __shared__ __align__(16) _Float16 row2[2][NB][PS];
    // h1 publication rows (written by l1, read by l2), tick parity
    __shared__ __align__(16) _Float16 pub1[2][NB][K][PS];
    // l1 input partials (Wih1 . h0(t)), f32, tick parity
    __shared__ __align__(16) float part1[2][NB][K][PS];
    __shared__ float h2f[NB][HID];
    __shared__ float mbuf[NB][HID];

    const int tid  = threadIdx.x;
    const int l    = tid >> 6;        // wave == layer
    const int lane = tid & 63;
    const int bl   = lane >> 5;       // batch half
    const int jj   = lane & 31;
    const bool act = (jj < HID);
    const int uL   = act ? jj : (jj - 8);   // pad lanes duplicate units 16-23
    const int bg   = blockIdx.x * NB + bl;

    // ---- packed-f16 weights in named int4v registers (natural pair order) ----
    int4v whA, whB, whC;              // own-h row for this wave's layer
    int4v wiA = {0,0,0,0}, wiB = {0,0,0,0}, wiC = {0,0,0,0};
    // l0: wi* = Wih1 row (partial weights);  l2: wi* = Wih2 row;  l1: unused
    float wx0 = 0.f, bias;

#define MK3(ROW, DA, DB, DC) do {                                                   \
        DA = (int4v){PKF((ROW)[0], (ROW)[1]),   PKF((ROW)[2], (ROW)[3]),            \
                     PKF((ROW)[4], (ROW)[5]),   PKF((ROW)[6], (ROW)[7])};           \
        DB = (int4v){PKF((ROW)[8], (ROW)[9]),   PKF((ROW)[10], (ROW)[11]),          \
                     PKF((ROW)[12], (ROW)[13]), PKF((ROW)[14], (ROW)[15])};         \
        DC = (int4v){PKF((ROW)[16], (ROW)[17]), PKF((ROW)[18], (ROW)[19]),          \
                     PKF((ROW)[20], (ROW)[21]), PKF((ROW)[22], (ROW)[23])};         \
    } while (0)

    if (l == 0) {
        MK3(Whh0 + uL * HID, whA, whB, whC);
        MK3(Wih1 + uL * HID, wiA, wiB, wiC);   // partial weights (output unit uL)
        wx0  = Wih0[uL];
        bias = bih0[uL] + bhh0[uL];
    } else if (l == 1) {
        MK3(Whh1 + uL * HID, whA, whB, whC);
        bias = bih1[uL] + bhh1[uL];
    } else {
        MK3(Whh2 + uL * HID, whA, whB, whC);
        MK3(Wih2 + uL * HID, wiA, wiB, wiC);
        bias = bih2[uL] + bhh2[uL];
    }
#undef MK3

    float cur = h_in[(l * BATCH + bg) * HID + uL];

    // ---- persistent own-row registers, seeded via one write + read-back ----
    int4v o0, o1, o2;
    if (l == 0) {
        row0[1][bl][jj] = (_Float16)cur;
        const int4v* r = (const int4v*)&row0[1][bl][0];
        o0 = r[0]; o1 = r[1]; o2 = r[2];
    } else if (l == 1) {
        pub1[0][bl][K - 1][jj] = (_Float16)cur;
        const int4v* r = (const int4v*)&pub1[0][bl][K - 1][0];
        o0 = r[0]; o1 = r[1]; o2 = r[2];
    } else {
        row2[1][bl][jj] = (_Float16)cur;
        const int4v* r = (const int4v*)&row2[1][bl][0];
        o0 = r[0]; o1 = r[1]; o2 = r[2];
    }

    // ---- x quads in registers (l0): 8 current + 8 prefetch ----
    const float* xrow = x + (size_t)bg * T_LEN;
    float4 xq[8], xn[8];
    if (l == 0) {
        const float4* xr = (const float4*)xrow;
        #pragma unroll
        for (int q = 0; q < 8; ++q) xq[q] = xr[q];
    }
#define XV(S)                                                                       \
    (((S) & 3) == 0 ? xq[(S) >> 2].x : ((S) & 3) == 1 ? xq[(S) >> 2].y              \
   : ((S) & 3) == 2 ? xq[(S) >> 2].z : xq[(S) >> 2].w)

// 12 packed dots of row triple (V0,V1,V2) vs weight triple into A0,A1
#define DOT12(V0_, V1_, V2_, W0_, W1_, W2_, A0_, A1_)                               \
    A0_ = dot2f(V0_.x, W0_.x, A0_); A1_ = dot2f(V0_.y, W0_.y, A1_);                 \
    A0_ = dot2f(V0_.z, W0_.z, A0_); A1_ = dot2f(V0_.w, W0_.w, A1_);                 \
    A0_ = dot2f(V1_.x, W1_.x, A0_); A1_ = dot2f(V1_.y, W1_.y, A1_);                 \
    A0_ = dot2f(V1_.z, W1_.z, A0_); A1_ = dot2f(V1_.w, W1_.w, A1_);                 \
    A0_ = dot2f(V2_.x, W2_.x, A0_); A1_ = dot2f(V2_.y, W2_.y, A1_);                 \
    A0_ = dot2f(V2_.z, W2_.z, A0_); A1_ = dot2f(V2_.w, W2_.w, A1_);

    __syncthreads();

    // ---- chunked, layer-skewed scan: tick c; l0->chunk c, l1->c-1, l2->c-2 ----
    for (int c = 0; c < CTOT; ++c) {
        const int wp = c & 1, rp = wp ^ 1;
        if (l == 0) {
            if (c < NC) {
                const bool pf = (c + 1 < NC);
                if (pf) {
                    const float4* xr = (const float4*)(xrow + (size_t)(c + 1) * K);
                    #pragma unroll
                    for (int q = 0; q < 8; ++q) xn[q] = xr[q];
                }
                float* dst = &part1[wp][bl][0][0];
                #pragma unroll
                for (int s = 0; s < K; ++s) {
                    // own dots from persistent regs (h0(t-1))
                    float a0 = fmaf(wx0, XV(s), bias), a1 = 0.f;
                    DOT12(o0, o1, o2, whA, whB, whC, a0, a1);
                    cur = fmaxf(a0 + a1, 0.f);
                    // write h0(t) and immediately issue read-back (in-order DS)
                    row0[s & 1][bl][jj] = (_Float16)cur;
                    const int4v* r = (const int4v*)&row0[s & 1][bl][0];
                    const int4v n0 = r[0], n1 = r[1], n2 = r[2];
                    // off-chain: l1's input partial for step t-1 (covers read latency)
                    if (s > 0) {
                        float p0 = 0.f, p1 = 0.f;
                        DOT12(o0, o1, o2, wiA, wiB, wiC, p0, p1);
                        dst[(s - 1) * PS + jj] = p0 + p1;
                    }
                    o0 = n0; o1 = n1; o2 = n2;
                }
                // epilogue partial for step K-1 straight from regs (no LDS re-read)
                {
                    float p0 = 0.f, p1 = 0.f;
                    DOT12(o0, o1, o2, wiA, wiB, wiC, p0, p1);
                    dst[(K - 1) * PS + jj] = p0 + p1;
                }
                if (pf) {
                    #pragma unroll
                    for (int q = 0; q < 8; ++q) xq[q] = xn[q];
                }
            }
        } else if (l == 1) {
            if (c >= 1 && c < 1 + NC) {
                const float* srcp = &part1[rp][bl][0][0];
                #pragma unroll
                for (int s = 0; s < K; ++s) {
                    const float pin = srcp[s * PS + jj];   // Wih1 . h0(t)
                    float a0 = pin + bias, a1 = 0.f;
                    DOT12(o0, o1, o2, whA, whB, whC, a0, a1);
                    cur = fmaxf(a0 + a1, 0.f);
                    // publish h1(t) and read back for next step
                    pub1[wp][bl][s][jj] = (_Float16)cur;
                    const int4v* r = (const int4v*)&pub1[wp][bl][s][0];
                    o0 = r[0]; o1 = r[1]; o2 = r[2];
                }
            }
        } else {
            if (c >= 2 && c < 2 + NC) {
                const int4v* src = (const int4v*)&pub1[rp][bl][0][0];
                int4v iA0 = src[0], iA1 = src[1], iA2 = src[2];
                #pragma unroll
                for (int s = 0; s < K; ++s) {
                    // input dots first (regs, independent of pending own read-back)
                    float a0 = bias, a1 = 0.f, a2 = 0.f, a3 = 0.f;
                    DOT12(iA0, iA1, iA2, wiA, wiB, wiC, a0, a1);   // Wih2.h1(t)
                    DOT12(o0, o1, o2, whA, whB, whC, a2, a3);      // Whh2.h2(t-1)
                    cur = fmaxf((a0 + a1) + (a2 + a3), 0.f);
                    row2[s & 1][bl][jj] = (_Float16)cur;
                    const int4v* r = (const int4v*)&row2[s & 1][bl][0];
                    const int4v n0 = r[0], n1 = r[1], n2 = r[2];
                    // off-chain: prefetch next input row (covers own read-back)
                    if (s + 1 < K) {
                        const int4v* nr = (const int4v*)&pub1[rp][bl][s + 1][0];
                        iA0 = nr[0]; iA1 = nr[1]; iA2 = nr[2];
                    }
                    o0 = n0; o1 = n1; o2 = n2;
                }
            }
        }
        __syncthreads();
    }
#undef XV
#undef DOT12

    // ---- h_final from f32 running values ----
    if (act) out[BATCH + (size_t)(l * BATCH + bg) * HID + uL] = cur;

    // ---- MLP head on h2(T-1) ----
    if (l == 2 && act) h2f[bl][uL] = cur;
    __syncthreads();
    if (l == 2 && act) {
        const float4* w1r = (const float4*)(W1 + uL * HID);
        const float4* hv  = (const float4*)&h2f[bl][0];
        float a = b1[uL];
        a = dot4(w1r[0], hv[0], a); a = dot4(w1r[1], hv[1], a);
        a = dot4(w1r[2], hv[2], a); a = dot4(w1r[3], hv[3], a);
        a = dot4(w1r[4], hv[4], a); a = dot4(w1r[5], hv[5], a);
        mbuf[bl][uL] = fmaxf(a, 0.f);
    }
    __syncthreads();
    if (l == 2 && jj == 0) {
        float a = b2[0];
        #pragma unroll
        for (int k = 0; k < HID; ++k) a = fmaf(W2[k], mbuf[bl][k], a);
        out[bg] = fmaxf(a, 0.f);
    }
}

extern "C" void kernel_launch(void* const* d_in, const int* in_sizes, int n_in,
                              void* d_out, int out_size, void* d_ws, size_t ws_size,
                              hipStream_t stream) {
    const float* x    = (const float*)d_in[0];
    const float* h_in = (const float*)d_in[1];
    const float* Wih0 = (const float*)d_in[2];
    const float* bih0 = (const float*)d_in[3];
    const float* Whh0 = (const float*)d_in[4];
    const float* bhh0 = (const float*)d_in[5];
    const float* Wih1 = (const float*)d_in[6];
    const float* bih1 = (const float*)d_in[7];
    const float* Whh1 = (const float*)d_in[8];
    const float* bhh1 = (const float*)d_in[9];
    const float* Wih2 = (const float*)d_in[10];
    const float* bih2 = (const float*)d_in[11];
    const float* Whh2 = (const float*)d_in[12];
    const float* bhh2 = (const float*)d_in[13];
    const float* W1   = (const float*)d_in[14];
    const float* b1   = (const float*)d_in[15];
    const float* W2   = (const float*)d_in[16];
    const float* b2   = (const float*)d_in[17];
    float* out = (float*)d_out;

    dim3 grid(BATCH / NB);   // 512 blocks -> 2 blocks/CU, 6 waves/CU
    dim3 block(TPB);         // 3 waves (wave == layer)
    hipLaunchKernelGGL(rnn_ra_kernel, grid, block, 0, stream,
                       x, h_in, Wih0, bih0, Whh0, bhh0,
                       Wih1, bih1, Whh1, bhh1, Wih2, bih2, Whh2, bhh2,
                       W1, b1, W2, b2, out);
}